// Round 1
// baseline (41.462 us; speedup 1.0000x reference)
//
#include <hip/hip_runtime.h>
#include <math.h>

#define BB 64
#define KMAX 512
#define DD 256
#define CC 1000

__device__ __forceinline__ float wave_reduce_sum(float v) {
    #pragma unroll
    for (int off = 32; off > 0; off >>= 1) v += __shfl_xor(v, off, 64);
    return v;
}
__device__ __forceinline__ float wave_reduce_max(float v) {
    #pragma unroll
    for (int off = 32; off > 0; off >>= 1) v = fmaxf(v, __shfl_xor(v, off, 64));
    return v;
}

// Kernel 1: s[b,k] = -w[b,k] * || deep[b] - n[b,k] ||
// One wave (64 lanes) per row; float4 loads cover D=256 exactly.
__global__ void dos_dist_kernel(const float* __restrict__ deep,
                                const float* __restrict__ n,
                                const float* __restrict__ w,
                                float* __restrict__ s_out) {
    const int wid  = threadIdx.x >> 6;
    const int lane = threadIdx.x & 63;
    const int row  = blockIdx.x * 4 + wid;          // row in [0, B*KMAX)
    const int b    = row >> 9;                      // KMAX = 512
    const float4 dv = ((const float4*)(deep + (size_t)b * DD))[lane];
    const float4 nv = ((const float4*)(n + (size_t)row * DD))[lane];
    const float dx = dv.x - nv.x, dy = dv.y - nv.y;
    const float dz = dv.z - nv.z, dw = dv.w - nv.w;
    float acc = dx*dx + dy*dy + dz*dz + dw*dw;
    acc = wave_reduce_sum(acc);
    if (lane == 0) s_out[row] = -w[row] * sqrtf(acc);
}

// Kernel 2: ce[b,k] = -log_softmax(cls[b,k,:])[target[b]]
// One 256-thread block per (b,k) row; 250 float4 loads cover C=1000.
__global__ void dos_ce_kernel(const float* __restrict__ cls,
                              const int* __restrict__ target,
                              float* __restrict__ ce_out) {
    const int row = blockIdx.x;                     // b*KMAX + k
    const int b   = row >> 9;
    const float* __restrict__ x = cls + (size_t)row * CC;
    const int t = threadIdx.x;

    float4 v = make_float4(-1e30f, -1e30f, -1e30f, -1e30f);
    if (t < 250) v = ((const float4*)x)[t];

    float m = fmaxf(fmaxf(v.x, v.y), fmaxf(v.z, v.w));
    __shared__ float smax[4];
    m = wave_reduce_max(m);
    if ((t & 63) == 0) smax[t >> 6] = m;
    __syncthreads();
    m = fmaxf(fmaxf(smax[0], smax[1]), fmaxf(smax[2], smax[3]));

    float e = 0.f;
    if (t < 250)
        e = __expf(v.x - m) + __expf(v.y - m) + __expf(v.z - m) + __expf(v.w - m);
    __shared__ float ssum[4];
    e = wave_reduce_sum(e);
    if ((t & 63) == 0) ssum[t >> 6] = e;
    __syncthreads();

    if (t == 0) {
        const float sum = ssum[0] + ssum[1] + ssum[2] + ssum[3];
        const float xt  = x[target[b]];
        ce_out[row] = -(xt - m - logf(sum));
    }
}

// Kernel 3: per-b masked softmax over K fused with the two reductions.
// part[b] = sum_k(valid) s  +  ( sum_k(valid) exp(s-m)*ce ) / ( sum_k(valid) exp(s-m) )
__global__ void dos_combine_kernel(const float* __restrict__ s,
                                   const float* __restrict__ ce,
                                   const int* __restrict__ lengths,
                                   float* __restrict__ part) {
    const int b = blockIdx.x;
    const int k = threadIdx.x;                      // 512 threads = KMAX
    const int len = lengths[b];
    const bool valid = k < len;

    const float sv = s[b * KMAX + k];
    const float cv = ce[b * KMAX + k];

    __shared__ float redm[8];
    float m = wave_reduce_max(valid ? sv : -1e30f);
    if ((k & 63) == 0) redm[k >> 6] = m;
    __syncthreads();
    float m8 = redm[0];
    #pragma unroll
    for (int i = 1; i < 8; i++) m8 = fmaxf(m8, redm[i]);

    float e  = valid ? __expf(sv - m8) : 0.f;
    float fs = valid ? sv : 0.f;
    float ec = e * cv;

    e  = wave_reduce_sum(e);
    fs = wave_reduce_sum(fs);
    ec = wave_reduce_sum(ec);

    __shared__ float r1[8], r2[8], r3[8];
    if ((k & 63) == 0) { r1[k >> 6] = e; r2[k >> 6] = fs; r3[k >> 6] = ec; }
    __syncthreads();
    if (k == 0) {
        float se = 0.f, sf = 0.f, sc = 0.f;
        #pragma unroll
        for (int i = 0; i < 8; i++) { se += r1[i]; sf += r2[i]; sc += r3[i]; }
        part[b] = sf + sc / se;
    }
}

// Kernel 4: sum 64 per-b partials -> out[0]. Overwrites every call (replay-safe).
__global__ void dos_final_kernel(const float* __restrict__ part,
                                 float* __restrict__ out) {
    float v = part[threadIdx.x];                    // 64 threads
    v = wave_reduce_sum(v);
    if (threadIdx.x == 0) out[0] = v;
}

extern "C" void kernel_launch(void* const* d_in, const int* in_sizes, int n_in,
                              void* d_out, int out_size, void* d_ws, size_t ws_size,
                              hipStream_t stream) {
    const float* deep    = (const float*)d_in[0];   // [B, D]
    const float* n       = (const float*)d_in[1];   // [B, KMAX, D]
    const float* w       = (const float*)d_in[2];   // [B, KMAX]
    const float* cls     = (const float*)d_in[3];   // [B, KMAX, C]
    const int*   target  = (const int*)d_in[4];     // [B]
    const int*   lengths = (const int*)d_in[5];     // [B]
    float*       out     = (float*)d_out;

    float* ws   = (float*)d_ws;
    float* s    = ws;                               // B*KMAX floats
    float* ce   = ws + BB * KMAX;                   // B*KMAX floats
    float* part = ws + 2 * BB * KMAX;               // B floats

    dos_dist_kernel<<<(BB * KMAX) / 4, 256, 0, stream>>>(deep, n, w, s);
    dos_ce_kernel<<<BB * KMAX, 256, 0, stream>>>(cls, target, ce);
    dos_combine_kernel<<<BB, KMAX, 0, stream>>>(s, ce, lengths, part);
    dos_final_kernel<<<1, 64, 0, stream>>>(part, out);
}

// Round 2
// 23.937 us; speedup vs baseline: 1.7321x; 1.7321x over previous
//
#include <hip/hip_runtime.h>
#include <math.h>

#define BB 64
#define KMAX 512
#define DD 256
#define CC 1000

__device__ __forceinline__ float wave_reduce_sum(float v) {
    #pragma unroll
    for (int off = 32; off > 0; off >>= 1) v += __shfl_xor(v, off, 64);
    return v;
}
__device__ __forceinline__ float wave_reduce_max(float v) {
    #pragma unroll
    for (int off = 32; off > 0; off >>= 1) v = fmaxf(v, __shfl_xor(v, off, 64));
    return v;
}

// Fused per-row kernel: one 64-lane wave per (b,k) row.
//   s[b,k]  = -w[b,k] * ||deep[b] - n[b,k]||        (D = 256 -> 1 float4/lane)
//   ce[b,k] = -log_softmax(cls[b,k,:])[target[b]]    (C = 1000 -> 4 float4/lane)
// Rows with k >= lengths[b] are never consumed downstream -> whole wave exits
// before touching memory, cutting HBM traffic roughly in half on this input.
__global__ void dos_row_kernel(const float* __restrict__ deep,
                               const float* __restrict__ n,
                               const float* __restrict__ w,
                               const float* __restrict__ cls,
                               const int* __restrict__ target,
                               const int* __restrict__ lengths,
                               float* __restrict__ s_out,
                               float* __restrict__ ce_out) {
    const int wid  = threadIdx.x >> 6;
    const int lane = threadIdx.x & 63;
    const int row  = blockIdx.x * 4 + wid;          // b*KMAX + k
    const int b    = row >> 9;                      // KMAX = 512
    const int k    = row & (KMAX - 1);
    if (k >= lengths[b]) return;                    // wave-uniform early exit

    // ---- issue all loads up front (overlap latencies) ----
    const float4 dv = ((const float4*)(deep + (size_t)b * DD))[lane];
    const float4 nv = ((const float4*)(n + (size_t)row * DD))[lane];
    const float* __restrict__ x = cls + (size_t)row * CC;
    const float4 v0 = ((const float4*)x)[lane];
    const float4 v1 = ((const float4*)x)[lane + 64];
    const float4 v2 = ((const float4*)x)[lane + 128];
    float4 v3 = make_float4(-1e30f, -1e30f, -1e30f, -1e30f);
    if (lane < 250 - 192) v3 = ((const float4*)x)[lane + 192];  // 250 float4 total

    // ---- dist ----
    const float dx = dv.x - nv.x, dy = dv.y - nv.y;
    const float dz = dv.z - nv.z, dw = dv.w - nv.w;
    float acc = dx*dx + dy*dy + dz*dz + dw*dw;
    acc = wave_reduce_sum(acc);

    // ---- ce: max ----
    float m = fmaxf(fmaxf(v0.x, v0.y), fmaxf(v0.z, v0.w));
    m = fmaxf(m, fmaxf(fmaxf(v1.x, v1.y), fmaxf(v1.z, v1.w)));
    m = fmaxf(m, fmaxf(fmaxf(v2.x, v2.y), fmaxf(v2.z, v2.w)));
    m = fmaxf(m, fmaxf(fmaxf(v3.x, v3.y), fmaxf(v3.z, v3.w)));
    m = wave_reduce_max(m);

    // ---- ce: sum of exp (v3 fill of -1e30 underflows to exactly 0) ----
    float e = __expf(v0.x - m) + __expf(v0.y - m) + __expf(v0.z - m) + __expf(v0.w - m)
            + __expf(v1.x - m) + __expf(v1.y - m) + __expf(v1.z - m) + __expf(v1.w - m)
            + __expf(v2.x - m) + __expf(v2.y - m) + __expf(v2.z - m) + __expf(v2.w - m)
            + __expf(v3.x - m) + __expf(v3.y - m) + __expf(v3.z - m) + __expf(v3.w - m);
    e = wave_reduce_sum(e);

    if (lane == 0) {
        s_out[row]  = -w[row] * sqrtf(acc);
        ce_out[row] = -(x[target[b]] - m - logf(e));   // x[t] is L1/L2 hot (just streamed)
    }
}

// Per-b masked softmax over K fused with the two reductions.
// part[b] = sum_k(valid) s  +  ( sum_k(valid) exp(s-m)*ce ) / ( sum_k(valid) exp(s-m) )
__global__ void dos_combine_kernel(const float* __restrict__ s,
                                   const float* __restrict__ ce,
                                   const int* __restrict__ lengths,
                                   float* __restrict__ part) {
    const int b = blockIdx.x;
    const int k = threadIdx.x;                      // 512 threads = KMAX
    const int len = lengths[b];
    const bool valid = k < len;

    const float sv = s[b * KMAX + k];               // invalid entries: poisoned, never used
    const float cv = ce[b * KMAX + k];

    __shared__ float redm[8];
    float m = wave_reduce_max(valid ? sv : -1e30f);
    if ((k & 63) == 0) redm[k >> 6] = m;
    __syncthreads();
    float m8 = redm[0];
    #pragma unroll
    for (int i = 1; i < 8; i++) m8 = fmaxf(m8, redm[i]);

    float e  = valid ? __expf(sv - m8) : 0.f;
    float fs = valid ? sv : 0.f;
    float ec = valid ? e * cv : 0.f;

    e  = wave_reduce_sum(e);
    fs = wave_reduce_sum(fs);
    ec = wave_reduce_sum(ec);

    __shared__ float r1[8], r2[8], r3[8];
    if ((k & 63) == 0) { r1[k >> 6] = e; r2[k >> 6] = fs; r3[k >> 6] = ec; }
    __syncthreads();
    if (k == 0) {
        float se = 0.f, sf = 0.f, sc = 0.f;
        #pragma unroll
        for (int i = 0; i < 8; i++) { se += r1[i]; sf += r2[i]; sc += r3[i]; }
        part[b] = sf + sc / se;
    }
}

// Sum 64 per-b partials -> out[0]. Overwrites every call (replay-safe).
__global__ void dos_final_kernel(const float* __restrict__ part,
                                 float* __restrict__ out) {
    float v = part[threadIdx.x];                    // 64 threads
    v = wave_reduce_sum(v);
    if (threadIdx.x == 0) out[0] = v;
}

extern "C" void kernel_launch(void* const* d_in, const int* in_sizes, int n_in,
                              void* d_out, int out_size, void* d_ws, size_t ws_size,
                              hipStream_t stream) {
    const float* deep    = (const float*)d_in[0];   // [B, D]
    const float* n       = (const float*)d_in[1];   // [B, KMAX, D]
    const float* w       = (const float*)d_in[2];   // [B, KMAX]
    const float* cls     = (const float*)d_in[3];   // [B, KMAX, C]
    const int*   target  = (const int*)d_in[4];     // [B]
    const int*   lengths = (const int*)d_in[5];     // [B]
    float*       out     = (float*)d_out;

    float* ws   = (float*)d_ws;
    float* s    = ws;                               // B*KMAX floats
    float* ce   = ws + BB * KMAX;                   // B*KMAX floats
    float* part = ws + 2 * BB * KMAX;               // B floats

    dos_row_kernel<<<(BB * KMAX) / 4, 256, 0, stream>>>(deep, n, w, cls, target,
                                                        lengths, s, ce);
    dos_combine_kernel<<<BB, KMAX, 0, stream>>>(s, ce, lengths, part);
    dos_final_kernel<<<1, 64, 0, stream>>>(part, out);
}